// Round 12
// baseline (787.751 us; speedup 1.0000x reference)
//
#include <hip/hip_runtime.h>
#include <hip/hip_bf16.h>

// MoE: T=2048, H=2048, I=5632, E=8, top-2 renormalized.
// route -> lists -> cvt x bf16 (scratch=d_out) -> GEMM1 (x@w1^T SwiGLU -> bf16 h)
// -> memset out -> GEMM2 (h@w2^T * w, atomicAdd).
// R12 = R11 (512-thr, 256-tall tiles, glds A-staging, reg-roundtrip B) + expert->XCD
// remap with n-FASTEST ordering: co-resident blocks on an XCD share A rows (2MB,
// L2-resident) but stream DIFFERENT B panels (no R8-style MSHR convoy).
// Lessons: asm-fence pipelines spill (R4/R5); deep pipelines null (R6/R7); mt-fastest
// XCD clustering convoys on B (R8); occupancy not the binder (R10); traffic is (R11).

#define TT 2048
#define HH 2048
#define II 5632
#define NE 8

using f32x4  = __attribute__((ext_vector_type(4))) float;
using bf16x8 = __attribute__((ext_vector_type(8))) short;

__device__ __forceinline__ uint32_t bfbits(float f) {
    __hip_bfloat16 h = __float2bfloat16(f);
    unsigned short u;
    __builtin_memcpy(&u, &h, 2);
    return (uint32_t)u;
}
__device__ __forceinline__ uint32_t pk2(float a, float b) {
    return bfbits(a) | (bfbits(b) << 16);
}
__device__ __forceinline__ uint4 pk8(const float4& a, const float4& b) {
    uint4 r;
    r.x = pk2(a.x, a.y); r.y = pk2(a.z, a.w);
    r.z = pk2(b.x, b.y); r.w = pk2(b.z, b.w);
    return r;
}
__device__ __forceinline__ void gl16(const void* g, void* l) {
    __builtin_amdgcn_global_load_lds(
        (const __attribute__((address_space(1))) unsigned int*)g,
        (__attribute__((address_space(3))) unsigned int*)l, 16, 0, 0);
}

// ---------------- x -> bf16 ----------------
__global__ void cvt_x(const float* __restrict__ x, __hip_bfloat16* __restrict__ xb) {
    const int i = (blockIdx.x * 256 + threadIdx.x) * 8;
    float4 a = *(const float4*)(x + i);
    float4 b = *(const float4*)(x + i + 4);
    *(uint4*)(xb + i) = pk8(a, b);
}

// ---------------- routing ----------------
__global__ void route_topk(const float* __restrict__ gating,
                           int* __restrict__ tk_idx, float* __restrict__ tk_w) {
    int t = blockIdx.x * 256 + threadIdx.x;
    if (t >= TT) return;
    float g[NE];
#pragma unroll
    for (int e = 0; e < NE; e++) g[e] = gating[t * NE + e];
    int i0 = 0; float b0 = g[0];
#pragma unroll
    for (int e = 1; e < NE; e++) if (g[e] > b0) { b0 = g[e]; i0 = e; }
    int i1 = (i0 == 0) ? 1 : 0; float b1 = g[i1];
#pragma unroll
    for (int e = 0; e < NE; e++) if (e != i0 && g[e] > b1) { b1 = g[e]; i1 = e; }
    float ex = expf(b1 - b0);
    float w0 = 1.f / (1.f + ex);
    float w1 = ex / (1.f + ex);
    tk_idx[2 * t] = i0; tk_idx[2 * t + 1] = i1;
    tk_w[2 * t] = w0;  tk_w[2 * t + 1] = w1;
}

__global__ void build_lists(const int* __restrict__ tk_idx, const float* __restrict__ tk_w,
                            int* __restrict__ list_tok, float* __restrict__ list_w,
                            int* __restrict__ counts) {
    const int e = blockIdx.x;
    const int tid = threadIdx.x;
    int flag[8]; float wt[8];
    int cnt = 0;
#pragma unroll
    for (int j = 0; j < 8; j++) {
        int t = tid * 8 + j;
        int f = -1;
        if (tk_idx[2 * t] == e) f = 0;
        else if (tk_idx[2 * t + 1] == e) f = 1;
        flag[j] = f;
        wt[j] = (f >= 0) ? tk_w[2 * t + f] : 0.f;
        cnt += (f >= 0) ? 1 : 0;
    }
    __shared__ int s[256];
    s[tid] = cnt;
    __syncthreads();
    for (int d = 1; d < 256; d <<= 1) {
        int v = (tid >= d) ? s[tid - d] : 0;
        __syncthreads();
        s[tid] += v;
        __syncthreads();
    }
    int pos = s[tid] - cnt;
#pragma unroll
    for (int j = 0; j < 8; j++) {
        if (flag[j] >= 0) {
            list_tok[e * TT + pos] = tid * 8 + j;
            list_w[e * TT + pos] = wt[j];
            pos++;
        }
    }
    if (tid == 255) counts[e] = s[255];
}

// ---------------- GEMM1: tile 256(M) x 64 I-cols, BK=32, 512 thr / 8 waves ----------------
// Grid: 5632 blocks 1-D. wid=(bid%8)*704+bid/8 -> XCD owns one expert.
// Decode wid: e = wid/704; mt = (wid%704)/88 (slow); n = wid%88 (fast).
__global__ __launch_bounds__(512, 4) void gemm1_swiglu(
    const __hip_bfloat16* __restrict__ xb, const float* __restrict__ w1,
    const int* __restrict__ list_tok, const int* __restrict__ counts,
    __hip_bfloat16* __restrict__ hbuf) {
    const int bid = blockIdx.x;
    const int wid = (bid & 7) * 704 + (bid >> 3);
    const int e   = wid / 704;
    const int rem = wid - e * 704;
    const int mt  = rem / 88;
    const int n0  = (rem - mt * 88) * 64;

    const int cnt = counts[e];
    const int row0 = mt * 256;
    if (row0 >= cnt) return;
    int off = 0;
#pragma unroll
    for (int i = 0; i < NE; i++) if (i < e) off += counts[i];
    const int valid = min(256, cnt - row0);
    const int tid = threadIdx.x;
    const int w = tid >> 6, l = tid & 63;   // 8 waves

    __shared__ uint4 As[2 * 1024];  // [buf][row 0..255][slot 0..3] linear; src pre-swizzled
    __shared__ uint4 Bs[2][512];    // [buf][row 0..127][slot] (g rows 0..63, u rows 64..127)

    // A staging: call c covers rows c*128 + w*16 + (l>>2)
    const char *aSrc0, *aSrc1;
    {
        int r0 = w * 16 + (l >> 2);
        int r1 = r0 + 128;
        int t0 = list_tok[e * TT + row0 + min(r0, valid - 1)];
        int t1 = list_tok[e * TT + row0 + min(r1, valid - 1)];
        int s0 = (l & 3) ^ ((r0 >> 1) & 3);
        int s1 = (l & 3) ^ ((r1 >> 1) & 3);
        aSrc0 = (const char*)(xb + (size_t)t0 * HH + s0 * 8);
        aSrc1 = (const char*)(xb + (size_t)t1 * HH + s1 * 8);
    }
    auto STAGEA = [&](int kt, int b) {
        char* ab = (char*)As + b * 16384 + w * 1024;
        gl16(aSrc0 + (size_t)kt * 64, ab);
        gl16(aSrc1 + (size_t)kt * 64, ab + 8192);
    };

    // B staging: thread -> row br (0..127), slot bu2 (0..3); br<64 -> g, else u
    const int br = tid >> 2, bu2 = tid & 3;
    const float* bSrc;
    {
        const float* base = w1 + (size_t)e * (2 * II) * HH;
        int r = (br < 64) ? (n0 + br) : (II + n0 + (br - 64));
        bSrc = base + (size_t)r * HH + bu2 * 8;
    }
    const int bwi = br * 4 + (bu2 ^ ((br >> 1) & 3));

    float4 rBa, rBb;
    auto LOADB = [&](int kt) {
        const int k = kt * 32;
        rBa = *(const float4*)(bSrc + k); rBb = *(const float4*)(bSrc + k + 4);
    };
    auto STOREB = [&](int b) { Bs[b][bwi] = pk8(rBa, rBb); };

    // wave grid 4M x 2N; wave tile 64 rows x 32 cols
    const int wm = w >> 1, wn = w & 1;
    const int l15 = l & 15, ks = l >> 4;
    int aidx[4], bgidx[2], buidx[2];
#pragma unroll
    for (int m = 0; m < 4; m++) { int r = wm * 64 + m * 16 + l15; aidx[m] = r * 4 + (ks ^ ((r >> 1) & 3)); }
#pragma unroll
    for (int n = 0; n < 2; n++) {
        int cg = wn * 32 + n * 16 + l15;       // g row in Bs
        int cu = cg + 64;                       // u row in Bs
        bgidx[n] = cg * 4 + (ks ^ ((cg >> 1) & 3));
        buidx[n] = cu * 4 + (ks ^ ((cu >> 1) & 3));
    }

    f32x4 accg[4][2], accu[4][2];
#pragma unroll
    for (int m = 0; m < 4; m++)
#pragma unroll
        for (int n = 0; n < 2; n++) { accg[m][n] = 0; accu[m][n] = 0; }

    STAGEA(0, 0); LOADB(0); STOREB(0);
    __syncthreads();
    const int KT = HH / 32;  // 64
#pragma unroll 2
    for (int kt = 0; kt < KT; ++kt) {
        const int cur = kt & 1;
        if (kt + 1 < KT) {
            STAGEA(kt + 1, cur ^ 1);
            LOADB(kt + 1);
        }
        bf16x8 gf[2], uf[2];
#pragma unroll
        for (int n = 0; n < 2; n++) {
            uint4 t = Bs[cur][bgidx[n]]; gf[n] = __builtin_bit_cast(bf16x8, t);
            uint4 t2 = Bs[cur][buidx[n]]; uf[n] = __builtin_bit_cast(bf16x8, t2);
        }
        const uint4* Ab = As + cur * 1024;
#pragma unroll
        for (int m = 0; m < 4; m++) {
            uint4 t = Ab[aidx[m]];
            bf16x8 af = __builtin_bit_cast(bf16x8, t);
#pragma unroll
            for (int n = 0; n < 2; n++) {
                accg[m][n] = __builtin_amdgcn_mfma_f32_16x16x32_bf16(af, gf[n], accg[m][n], 0, 0, 0);
                accu[m][n] = __builtin_amdgcn_mfma_f32_16x16x32_bf16(af, uf[n], accu[m][n], 0, 0, 0);
            }
        }
        if (kt + 1 < KT) STOREB(cur ^ 1);
        __syncthreads();
    }

    // epilogue: h = silu(g)*u -> bf16
#pragma unroll
    for (int m = 0; m < 4; m++) {
#pragma unroll
        for (int r = 0; r < 4; r++) {
            const int lr = wm * 64 + m * 16 + ks * 4 + r;
            if (lr < valid) {
                __hip_bfloat16* hrow = hbuf + (size_t)(off + row0 + lr) * II;
#pragma unroll
                for (int n = 0; n < 2; n++) {
                    const int col = n0 + wn * 32 + n * 16 + l15;
                    float g = accg[m][n][r], u = accu[m][n][r];
                    float h = g / (1.f + __expf(-g)) * u;
                    hrow[col] = __float2bfloat16(h);
                }
            }
        }
    }
}

// ---------------- GEMM2: tile 256(M) x 128(N), BK=32, 512 thr / 8 waves ----------------
// Grid: 1024 blocks 1-D. wid=(bid%8)*128+bid/8 -> XCD owns one expert.
// Decode: e = wid/128; mt = (wid%128)/16 (slow); n = wid%16 (fast).
__global__ __launch_bounds__(512, 4) void gemm2_scatter(
    const __hip_bfloat16* __restrict__ hbuf, const float* __restrict__ w2,
    const int* __restrict__ list_tok, const float* __restrict__ list_w,
    const int* __restrict__ counts, float* __restrict__ out) {
    const int bid = blockIdx.x;
    const int wid = (bid & 7) * 128 + (bid >> 3);
    const int e   = wid >> 7;
    const int rem = wid & 127;
    const int mt  = rem >> 4;
    const int n0  = (rem & 15) * 128;

    const int cnt = counts[e];
    const int row0 = mt * 256;
    if (row0 >= cnt) return;
    int off = 0;
#pragma unroll
    for (int i = 0; i < NE; i++) if (i < e) off += counts[i];
    const int valid = min(256, cnt - row0);
    const int tid = threadIdx.x;
    const int w = tid >> 6, l = tid & 63;

    __shared__ uint4 As[2 * 1024];  // 256 rows x 4 slots per buf
    __shared__ uint4 Bs[2][512];    // 128 rows x 4 slots per buf

    const char *aSrc0, *aSrc1;
    {
        int r0 = w * 16 + (l >> 2);
        int r1 = r0 + 128;
        int s0 = (l & 3) ^ ((r0 >> 1) & 3);
        int s1 = (l & 3) ^ ((r1 >> 1) & 3);
        aSrc0 = (const char*)(hbuf + (size_t)(off + row0 + min(r0, valid - 1)) * II + s0 * 8);
        aSrc1 = (const char*)(hbuf + (size_t)(off + row0 + min(r1, valid - 1)) * II + s1 * 8);
    }
    auto STAGEA = [&](int kt, int b) {
        char* ab = (char*)As + b * 16384 + w * 1024;
        gl16(aSrc0 + (size_t)kt * 64, ab);
        gl16(aSrc1 + (size_t)kt * 64, ab + 8192);
    };

    const int br = tid >> 2, bu2 = tid & 3;
    const float* bSrc = w2 + (size_t)e * HH * II + (size_t)(n0 + br) * II + bu2 * 8;
    const int bwi = br * 4 + (bu2 ^ ((br >> 1) & 3));

    float4 rBa, rBb;
    auto LOADB = [&](int kt) {
        const int k = kt * 32;
        rBa = *(const float4*)(bSrc + k); rBb = *(const float4*)(bSrc + k + 4);
    };
    auto STOREB = [&](int b) { Bs[b][bwi] = pk8(rBa, rBb); };

    // wave grid 2M x 4N; wave tile 128 rows x 32 cols
    const int wm = w >> 2, wn = w & 3;
    const int l15 = l & 15, ks = l >> 4;
    int aidx[8], bidx[2];
#pragma unroll
    for (int m = 0; m < 8; m++) { int r = wm * 128 + m * 16 + l15; aidx[m] = r * 4 + (ks ^ ((r >> 1) & 3)); }
#pragma unroll
    for (int n = 0; n < 2; n++) { int c = wn * 32 + n * 16 + l15; bidx[n] = c * 4 + (ks ^ ((c >> 1) & 3)); }

    f32x4 acc[8][2];
#pragma unroll
    for (int m = 0; m < 8; m++)
#pragma unroll
        for (int n = 0; n < 2; n++) acc[m][n] = 0;

    STAGEA(0, 0); LOADB(0); STOREB(0);
    __syncthreads();
    const int KT = II / 32;  // 176
#pragma unroll 2
    for (int kt = 0; kt < KT; ++kt) {
        const int cur = kt & 1;
        if (kt + 1 < KT) {
            STAGEA(kt + 1, cur ^ 1);
            LOADB(kt + 1);
        }
        bf16x8 bf[2];
#pragma unroll
        for (int n = 0; n < 2; n++) { uint4 t = Bs[cur][bidx[n]]; bf[n] = __builtin_bit_cast(bf16x8, t); }
        const uint4* Ab = As + cur * 1024;
#pragma unroll
        for (int m = 0; m < 8; m++) {
            uint4 t = Ab[aidx[m]];
            bf16x8 af = __builtin_bit_cast(bf16x8, t);
#pragma unroll
            for (int n = 0; n < 2; n++)
                acc[m][n] = __builtin_amdgcn_mfma_f32_16x16x32_bf16(af, bf[n], acc[m][n], 0, 0, 0);
        }
        if (kt + 1 < KT) STOREB(cur ^ 1);
        __syncthreads();
    }

    // epilogue: scale by routing weight, scatter-add
#pragma unroll
    for (int m = 0; m < 8; m++) {
#pragma unroll
        for (int r = 0; r < 4; r++) {
            const int lr = wm * 128 + m * 16 + ks * 4 + r;
            if (lr < valid) {
                const int tok = list_tok[e * TT + row0 + lr];
                const float wt = list_w[e * TT + row0 + lr];
                float* orow = out + (size_t)tok * HH;
#pragma unroll
                for (int n = 0; n < 2; n++) {
                    const int col = n0 + wn * 32 + n * 16 + l15;
                    atomicAdd(orow + col, acc[m][n][r] * wt);
                }
            }
        }
    }
}

extern "C" void kernel_launch(void* const* d_in, const int* in_sizes, int n_in,
                              void* d_out, int out_size, void* d_ws, size_t ws_size,
                              hipStream_t stream) {
    const float* x      = (const float*)d_in[0];
    const float* gating = (const float*)d_in[1];
    const float* w1     = (const float*)d_in[2];
    const float* w2     = (const float*)d_in[3];
    float* out = (float*)d_out;
    char* ws = (char*)d_ws;

    int*   list_tok = (int*)(ws + 0);              // 64 KB
    float* list_w   = (float*)(ws + (64 << 10));   // 64 KB
    int*   counts   = (int*)(ws + (128 << 10));    // 32 B
    int*   tk_idx   = (int*)(ws + (132 << 10));    // 16 KB
    float* tk_w     = (float*)(ws + (148 << 10));  // 16 KB
    __hip_bfloat16* hbuf = (__hip_bfloat16*)(ws + (1 << 20));  // 4096 x 5632 bf16 = 46.1 MB

    // xb (bf16 x, 8.4 MB) lives in d_out until gemm1 is done; memset before gemm2.
    __hip_bfloat16* xb = (__hip_bfloat16*)d_out;

    route_topk<<<TT / 256, 256, 0, stream>>>(gating, tk_idx, tk_w);
    build_lists<<<NE, 256, 0, stream>>>(tk_idx, tk_w, list_tok, list_w, counts);
    cvt_x<<<TT * HH / (256 * 8), 256, 0, stream>>>(x, xb);
    gemm1_swiglu<<<dim3(5632), 512, 0, stream>>>(xb, w1, list_tok, counts, hbuf);
    (void)hipMemsetAsync(d_out, 0, (size_t)TT * HH * sizeof(float), stream);
    gemm2_scatter<<<dim3(1024), 512, 0, stream>>>(hbuf, w2, list_tok, list_w, counts, out);
}

// Round 13
// 734.784 us; speedup vs baseline: 1.0721x; 1.0721x over previous
//
#include <hip/hip_runtime.h>
#include <hip/hip_bf16.h>

// MoE: T=2048, H=2048, I=5632, E=8, top-2 renormalized.
// route -> lists -> cvt x bf16 (scratch=d_out) -> GEMM1 (x@w1^T SwiGLU -> bf16 h)
// -> memset out -> GEMM2 (h@w2^T * w, atomicAdd).
// R13: traffic reduction via wider N at constant 64-AGPR/wave => 16-wave (1024-thr)
// blocks. gemm1 tile 256M x 128cols (A rereads 88->44): 2.6GB cache-side vs R11 3.5GB.
// gemm2 tile 256M x 256N: 1.4GB vs 1.85GB. Structure = R11 (glds A, reg-roundtrip B,
// plain dbuf). NO XCD remap (R8+R12 both regressed: dispatch assumption wrong).
// Lessons: asm-fence pipelines spill (R4/R5); deep pipelines null (R6/R7); occupancy
// not the binder (R10); bytes-moved is (R11: taller tiles => -7%).

#define TT 2048
#define HH 2048
#define II 5632
#define NE 8

using f32x4  = __attribute__((ext_vector_type(4))) float;
using bf16x8 = __attribute__((ext_vector_type(8))) short;

__device__ __forceinline__ uint32_t bfbits(float f) {
    __hip_bfloat16 h = __float2bfloat16(f);
    unsigned short u;
    __builtin_memcpy(&u, &h, 2);
    return (uint32_t)u;
}
__device__ __forceinline__ uint32_t pk2(float a, float b) {
    return bfbits(a) | (bfbits(b) << 16);
}
__device__ __forceinline__ uint4 pk8(const float4& a, const float4& b) {
    uint4 r;
    r.x = pk2(a.x, a.y); r.y = pk2(a.z, a.w);
    r.z = pk2(b.x, b.y); r.w = pk2(b.z, b.w);
    return r;
}
__device__ __forceinline__ void gl16(const void* g, void* l) {
    __builtin_amdgcn_global_load_lds(
        (const __attribute__((address_space(1))) unsigned int*)g,
        (__attribute__((address_space(3))) unsigned int*)l, 16, 0, 0);
}

// ---------------- x -> bf16 ----------------
__global__ void cvt_x(const float* __restrict__ x, __hip_bfloat16* __restrict__ xb) {
    const int i = (blockIdx.x * 256 + threadIdx.x) * 8;
    float4 a = *(const float4*)(x + i);
    float4 b = *(const float4*)(x + i + 4);
    *(uint4*)(xb + i) = pk8(a, b);
}

// ---------------- routing ----------------
__global__ void route_topk(const float* __restrict__ gating,
                           int* __restrict__ tk_idx, float* __restrict__ tk_w) {
    int t = blockIdx.x * 256 + threadIdx.x;
    if (t >= TT) return;
    float g[NE];
#pragma unroll
    for (int e = 0; e < NE; e++) g[e] = gating[t * NE + e];
    int i0 = 0; float b0 = g[0];
#pragma unroll
    for (int e = 1; e < NE; e++) if (g[e] > b0) { b0 = g[e]; i0 = e; }
    int i1 = (i0 == 0) ? 1 : 0; float b1 = g[i1];
#pragma unroll
    for (int e = 0; e < NE; e++) if (e != i0 && g[e] > b1) { b1 = g[e]; i1 = e; }
    float ex = expf(b1 - b0);
    float w0 = 1.f / (1.f + ex);
    float w1 = ex / (1.f + ex);
    tk_idx[2 * t] = i0; tk_idx[2 * t + 1] = i1;
    tk_w[2 * t] = w0;  tk_w[2 * t + 1] = w1;
}

__global__ void build_lists(const int* __restrict__ tk_idx, const float* __restrict__ tk_w,
                            int* __restrict__ list_tok, float* __restrict__ list_w,
                            int* __restrict__ counts) {
    const int e = blockIdx.x;
    const int tid = threadIdx.x;
    int flag[8]; float wt[8];
    int cnt = 0;
#pragma unroll
    for (int j = 0; j < 8; j++) {
        int t = tid * 8 + j;
        int f = -1;
        if (tk_idx[2 * t] == e) f = 0;
        else if (tk_idx[2 * t + 1] == e) f = 1;
        flag[j] = f;
        wt[j] = (f >= 0) ? tk_w[2 * t + f] : 0.f;
        cnt += (f >= 0) ? 1 : 0;
    }
    __shared__ int s[256];
    s[tid] = cnt;
    __syncthreads();
    for (int d = 1; d < 256; d <<= 1) {
        int v = (tid >= d) ? s[tid - d] : 0;
        __syncthreads();
        s[tid] += v;
        __syncthreads();
    }
    int pos = s[tid] - cnt;
#pragma unroll
    for (int j = 0; j < 8; j++) {
        if (flag[j] >= 0) {
            list_tok[e * TT + pos] = tid * 8 + j;
            list_w[e * TT + pos] = wt[j];
            pos++;
        }
    }
    if (tid == 255) counts[e] = s[255];
}

// ---------------- GEMM1: tile 256(M) x 128 I-cols, BK=32, 1024 thr / 16 waves ----------------
// Wave grid 4Mx4N, wave tile 64M x 32cols, dual acc(g,u) = 16 frags = 64 AGPR.
// LDS: A 16KB x2 (glds, 256 rows) + B 16KB x2 (256 weight rows: 128 g + 128 u) = 64KB.
__global__ __launch_bounds__(1024, 4) void gemm1_swiglu(
    const __hip_bfloat16* __restrict__ xb, const float* __restrict__ w1,
    const int* __restrict__ list_tok, const int* __restrict__ counts,
    __hip_bfloat16* __restrict__ hbuf) {
    const int e = blockIdx.y >> 3;
    const int mt = blockIdx.y & 7;
    const int cnt = counts[e];
    const int row0 = mt * 256;
    if (row0 >= cnt) return;
    int off = 0;
#pragma unroll
    for (int i = 0; i < NE; i++) if (i < e) off += counts[i];
    const int valid = min(256, cnt - row0);
    const int n0 = blockIdx.x * 128;
    const int tid = threadIdx.x;
    const int w = tid >> 6, l = tid & 63;   // 16 waves

    __shared__ uint4 As[2 * 1024];  // [buf][row 0..255][slot 0..3] linear; src pre-swizzled
    __shared__ uint4 Bs[2 * 1024];  // [buf][wrow 0..255][slot]: wrow<128 gate, else up

    // A staging: wave w covers rows w*16 + (l>>2); one gl16 per wave per K-step
    const char* aSrc;
    {
        int r = w * 16 + (l >> 2);
        int t0 = list_tok[e * TT + row0 + min(r, valid - 1)];
        int s0 = (l & 3) ^ ((r >> 1) & 3);
        aSrc = (const char*)(xb + (size_t)t0 * HH + s0 * 8);
    }
    auto STAGEA = [&](int kt, int b) {
        gl16(aSrc + (size_t)kt * 64, (char*)As + b * 16384 + w * 1024);
    };

    // B staging: thread -> wrow br (0..255), slot bu2 (0..3)
    const int br = tid >> 2, bu2 = tid & 3;
    const float* bSrc;
    {
        const float* base = w1 + (size_t)e * (2 * II) * HH;
        int r = (br < 128) ? (n0 + br) : (II + n0 + (br - 128));
        bSrc = base + (size_t)r * HH + bu2 * 8;
    }
    const int bwi = br * 4 + (bu2 ^ ((br >> 1) & 3));

    float4 rBa, rBb;
    auto LOADB = [&](int kt) {
        const int k = kt * 32;
        rBa = *(const float4*)(bSrc + k); rBb = *(const float4*)(bSrc + k + 4);
    };
    auto STOREB = [&](int b) { Bs[b * 1024 + bwi] = pk8(rBa, rBb); };

    // wave grid 4M x 4N; wave tile 64 rows x 32 cols (dual g,u)
    const int wm = w >> 2, wn = w & 3;
    const int l15 = l & 15, ks = l >> 4;
    int aidx[4], bgidx[2], buidx[2];
#pragma unroll
    for (int m = 0; m < 4; m++) { int r = wm * 64 + m * 16 + l15; aidx[m] = r * 4 + (ks ^ ((r >> 1) & 3)); }
#pragma unroll
    for (int n = 0; n < 2; n++) {
        int cg = wn * 32 + n * 16 + l15;        // gate wrow
        int cu = cg + 128;                       // up wrow
        bgidx[n] = cg * 4 + (ks ^ ((cg >> 1) & 3));
        buidx[n] = cu * 4 + (ks ^ ((cu >> 1) & 3));
    }

    f32x4 accg[4][2], accu[4][2];
#pragma unroll
    for (int m = 0; m < 4; m++)
#pragma unroll
        for (int n = 0; n < 2; n++) { accg[m][n] = 0; accu[m][n] = 0; }

    STAGEA(0, 0); LOADB(0); STOREB(0);
    __syncthreads();
    const int KT = HH / 32;  // 64
#pragma unroll 2
    for (int kt = 0; kt < KT; ++kt) {
        const int cur = kt & 1;
        if (kt + 1 < KT) {
            STAGEA(kt + 1, cur ^ 1);
            LOADB(kt + 1);
        }
        bf16x8 gf[2], uf[2];
#pragma unroll
        for (int n = 0; n < 2; n++) {
            uint4 t = Bs[cur * 1024 + bgidx[n]]; gf[n] = __builtin_bit_cast(bf16x8, t);
            uint4 t2 = Bs[cur * 1024 + buidx[n]]; uf[n] = __builtin_bit_cast(bf16x8, t2);
        }
        const uint4* Ab = As + cur * 1024;
#pragma unroll
        for (int m = 0; m < 4; m++) {
            uint4 t = Ab[aidx[m]];
            bf16x8 af = __builtin_bit_cast(bf16x8, t);
#pragma unroll
            for (int n = 0; n < 2; n++) {
                accg[m][n] = __builtin_amdgcn_mfma_f32_16x16x32_bf16(af, gf[n], accg[m][n], 0, 0, 0);
                accu[m][n] = __builtin_amdgcn_mfma_f32_16x16x32_bf16(af, uf[n], accu[m][n], 0, 0, 0);
            }
        }
        if (kt + 1 < KT) STOREB(cur ^ 1);
        __syncthreads();
    }

    // epilogue: h = silu(g)*u -> bf16
#pragma unroll
    for (int m = 0; m < 4; m++) {
#pragma unroll
        for (int r = 0; r < 4; r++) {
            const int lr = wm * 64 + m * 16 + ks * 4 + r;
            if (lr < valid) {
                __hip_bfloat16* hrow = hbuf + (size_t)(off + row0 + lr) * II;
#pragma unroll
                for (int n = 0; n < 2; n++) {
                    const int col = n0 + wn * 32 + n * 16 + l15;
                    float g = accg[m][n][r], u = accu[m][n][r];
                    float h = g / (1.f + __expf(-g)) * u;
                    hrow[col] = __float2bfloat16(h);
                }
            }
        }
    }
}

// ---------------- GEMM2: tile 256(M) x 256(N), BK=32, 1024 thr / 16 waves ----------------
// Wave grid 4Mx4N, wave tile 64x64, acc[4][4] = 16 frags = 64 AGPR.
// LDS: A 16KB x2 (glds) + B 16KB x2 (256 rows) = 64KB.
__global__ __launch_bounds__(1024, 4) void gemm2_scatter(
    const __hip_bfloat16* __restrict__ hbuf, const float* __restrict__ w2,
    const int* __restrict__ list_tok, const float* __restrict__ list_w,
    const int* __restrict__ counts, float* __restrict__ out) {
    const int e = blockIdx.y >> 3;
    const int mt = blockIdx.y & 7;
    const int cnt = counts[e];
    const int row0 = mt * 256;
    if (row0 >= cnt) return;
    int off = 0;
#pragma unroll
    for (int i = 0; i < NE; i++) if (i < e) off += counts[i];
    const int valid = min(256, cnt - row0);
    const int n0 = blockIdx.x * 256;
    const int tid = threadIdx.x;
    const int w = tid >> 6, l = tid & 63;

    __shared__ uint4 As[2 * 1024];  // 256 rows x 4 slots per buf
    __shared__ uint4 Bs[2 * 1024];  // 256 rows x 4 slots per buf

    const char* aSrc;
    {
        int r = w * 16 + (l >> 2);
        int s0 = (l & 3) ^ ((r >> 1) & 3);
        aSrc = (const char*)(hbuf + (size_t)(off + row0 + min(r, valid - 1)) * II + s0 * 8);
    }
    auto STAGEA = [&](int kt, int b) {
        gl16(aSrc + (size_t)kt * 64, (char*)As + b * 16384 + w * 1024);
    };

    const int br = tid >> 2, bu2 = tid & 3;
    const float* bSrc = w2 + (size_t)e * HH * II + (size_t)(n0 + br) * II + bu2 * 8;
    const int bwi = br * 4 + (bu2 ^ ((br >> 1) & 3));

    float4 rBa, rBb;
    auto LOADB = [&](int kt) {
        const int k = kt * 32;
        rBa = *(const float4*)(bSrc + k); rBb = *(const float4*)(bSrc + k + 4);
    };
    auto STOREB = [&](int b) { Bs[b * 1024 + bwi] = pk8(rBa, rBb); };

    // wave grid 4M x 4N; wave tile 64 x 64
    const int wm = w >> 2, wn = w & 3;
    const int l15 = l & 15, ks = l >> 4;
    int aidx[4], bidx[4];
#pragma unroll
    for (int m = 0; m < 4; m++) { int r = wm * 64 + m * 16 + l15; aidx[m] = r * 4 + (ks ^ ((r >> 1) & 3)); }
#pragma unroll
    for (int n = 0; n < 4; n++) { int c = wn * 64 + n * 16 + l15; bidx[n] = c * 4 + (ks ^ ((c >> 1) & 3)); }

    f32x4 acc[4][4];
#pragma unroll
    for (int m = 0; m < 4; m++)
#pragma unroll
        for (int n = 0; n < 4; n++) acc[m][n] = 0;

    STAGEA(0, 0); LOADB(0); STOREB(0);
    __syncthreads();
    const int KT = II / 32;  // 176
#pragma unroll 2
    for (int kt = 0; kt < KT; ++kt) {
        const int cur = kt & 1;
        if (kt + 1 < KT) {
            STAGEA(kt + 1, cur ^ 1);
            LOADB(kt + 1);
        }
        bf16x8 bf[4];
#pragma unroll
        for (int n = 0; n < 4; n++) { uint4 t = Bs[cur * 1024 + bidx[n]]; bf[n] = __builtin_bit_cast(bf16x8, t); }
        const uint4* Ab = As + cur * 1024;
#pragma unroll
        for (int m = 0; m < 4; m++) {
            uint4 t = Ab[aidx[m]];
            bf16x8 af = __builtin_bit_cast(bf16x8, t);
#pragma unroll
            for (int n = 0; n < 4; n++)
                acc[m][n] = __builtin_amdgcn_mfma_f32_16x16x32_bf16(af, bf[n], acc[m][n], 0, 0, 0);
        }
        if (kt + 1 < KT) STOREB(cur ^ 1);
        __syncthreads();
    }

    // epilogue: scale by routing weight, scatter-add
#pragma unroll
    for (int m = 0; m < 4; m++) {
#pragma unroll
        for (int r = 0; r < 4; r++) {
            const int lr = wm * 64 + m * 16 + ks * 4 + r;
            if (lr < valid) {
                const int tok = list_tok[e * TT + row0 + lr];
                const float wt = list_w[e * TT + row0 + lr];
                float* orow = out + (size_t)tok * HH;
#pragma unroll
                for (int n = 0; n < 4; n++) {
                    const int col = n0 + wn * 64 + n * 16 + l15;
                    atomicAdd(orow + col, acc[m][n][r] * wt);
                }
            }
        }
    }
}

extern "C" void kernel_launch(void* const* d_in, const int* in_sizes, int n_in,
                              void* d_out, int out_size, void* d_ws, size_t ws_size,
                              hipStream_t stream) {
    const float* x      = (const float*)d_in[0];
    const float* gating = (const float*)d_in[1];
    const float* w1     = (const float*)d_in[2];
    const float* w2     = (const float*)d_in[3];
    float* out = (float*)d_out;
    char* ws = (char*)d_ws;

    int*   list_tok = (int*)(ws + 0);              // 64 KB
    float* list_w   = (float*)(ws + (64 << 10));   // 64 KB
    int*   counts   = (int*)(ws + (128 << 10));    // 32 B
    int*   tk_idx   = (int*)(ws + (132 << 10));    // 16 KB
    float* tk_w     = (float*)(ws + (148 << 10));  // 16 KB
    __hip_bfloat16* hbuf = (__hip_bfloat16*)(ws + (1 << 20));  // 4096 x 5632 bf16 = 46.1 MB

    // xb (bf16 x, 8.4 MB) lives in d_out until gemm1 is done; memset before gemm2.
    __hip_bfloat16* xb = (__hip_bfloat16*)d_out;

    route_topk<<<TT / 256, 256, 0, stream>>>(gating, tk_idx, tk_w);
    build_lists<<<NE, 256, 0, stream>>>(tk_idx, tk_w, list_tok, list_w, counts);
    cvt_x<<<TT * HH / (256 * 8), 256, 0, stream>>>(x, xb);
    gemm1_swiglu<<<dim3(II / 128, NE * 8), 1024, 0, stream>>>(xb, w1, list_tok, counts, hbuf);
    (void)hipMemsetAsync(d_out, 0, (size_t)TT * HH * sizeof(float), stream);
    gemm2_scatter<<<dim3(HH / 256, NE * 8), 1024, 0, stream>>>(hbuf, w2, list_tok, list_w, counts, out);
}